// Round 5
// baseline (525.300 us; speedup 1.0000x reference)
//
#include <hip/hip_runtime.h>
#include <hip/hip_bf16.h>

#define BB 32
#define SS 2048
#define DD 1024
#define UU 1024
#define MBLK 64
#define KPH 256   // K per LDS phase
#define NPH 4     // DD / KPH

typedef short bf16x8 __attribute__((ext_vector_type(8)));
typedef float f32x4 __attribute__((ext_vector_type(4)));
typedef float f32x16 __attribute__((ext_vector_type(16)));
typedef int i32x4 __attribute__((ext_vector_type(4)));
typedef unsigned int u32;

__device__ __forceinline__ unsigned short f2bf(float x) {
    union { float f; unsigned int u; } v; v.f = x;
    unsigned int r = v.u + 0x7fffu + ((v.u >> 16) & 1u);
    return (unsigned short)(r >> 16);
}

__device__ __forceinline__ f32x4 ntload4(const float* p) {
    return __builtin_nontemporal_load(reinterpret_cast<const f32x4*>(p));
}

__device__ __forceinline__ u32 cvtpk(float lo, float hi) {
    u32 r;
    asm("v_cvt_pk_bf16_f32 %0, %1, %2" : "=v"(r) : "v"(lo), "v"(hi));
    return r;
}

// ---------------- K1a: q_proj = query@w1 + b1 + b2 ----------------
__global__ void qproj_kernel(const float* __restrict__ query, const float* __restrict__ w1,
                             const float* __restrict__ b1, const float* __restrict__ b2,
                             float* __restrict__ qp2) {
    __shared__ float qs[DD];
    const int b = blockIdx.x;   // 32
    const int uc = blockIdx.y;  // 4
    const int t = threadIdx.x;  // 256
    for (int i = t; i < DD; i += 256) qs[i] = query[b * DD + i];
    __syncthreads();
    const int u = uc * 256 + t;
    float acc = 0.f;
#pragma unroll 4
    for (int d = 0; d < DD; ++d) acc = fmaf(qs[d], w1[d * UU + u], acc);
    qp2[b * UU + u] = acc + b1[u] + b2[u];
}

// ---------------- K1b: w2t[u][d] = bf16(w2[d][u]) ----------------
__global__ void w2t_kernel(const float* __restrict__ w2, unsigned short* __restrict__ w2t) {
    __shared__ float tile[64][65];
    const int u0 = blockIdx.x * 64;
    const int d0 = blockIdx.y * 64;
    const int t = threadIdx.x;
    const int c = t & 63, rg = t >> 6;
#pragma unroll
    for (int rr = 0; rr < 16; ++rr) {
        int dl = rg * 16 + rr;
        tile[dl][c] = w2[(size_t)(d0 + dl) * UU + u0 + c];
    }
    __syncthreads();
#pragma unroll
    for (int rr = 0; rr < 16; ++rr) {
        int ul = rg * 16 + rr;
        w2t[(size_t)(u0 + ul) * DD + d0 + c] = f2bf(tile[c][ul]);
    }
}

// ---------------- K2: fused GEMM + tanh + wv-reduce -> score[b,s] ----------------
// 512 threads = 8 waves. 32x32x16 MFMA. Wave-tile 64x128 (all 1024 U-cols in one pass).
// A (values->bf16) double-buffered in LDS, KPH=256 x 4 phases, stage-loads overlap compute.
// B (w2t) from L2 with depth-1 register prefetch.
__global__ __launch_bounds__(512, 2)
void score_kernel(const float* __restrict__ values, const unsigned short* __restrict__ w2t,
                  const float* __restrict__ qp2, const float* __restrict__ wv,
                  const float* __restrict__ bv, float* __restrict__ score) {
    __shared__ __align__(16) unsigned short Vs[2][MBLK * KPH];  // 2 x 32 KB
    __shared__ float ssum[8][MBLK];

    const int blk = blockIdx.x;       // 1024
    const int b = blk >> 5;
    const int s0 = (blk & 31) * MBLK;
    const int tid = threadIdx.x;
    const int lane = tid & 63;
    const int wid = tid >> 6;          // 0..7

    const int col = lane & 31;         // frag row (A) / frag col (B, D)
    const int khalf = (lane >> 5) * 8; // k offset within frag
    const int nb = wid * 128;          // this wave's 128-col U-slice

    // staging: 64 rows x 256 cols, 8 threads/row x 32 elems
    const int srow = tid >> 3;
    const int scol = (tid & 7) * 32;
    const int swz = (srow & 7) << 3;
    const float* sbase = values + ((size_t)b * SS + s0 + srow) * DD + scol;

    const unsigned short* wb = w2t + (size_t)(nb + col) * DD + khalf;

    f32x16 acc[2][4];
#pragma unroll
    for (int mg = 0; mg < 2; ++mg)
#pragma unroll
        for (int ng = 0; ng < 4; ++ng)
#pragma unroll
            for (int r = 0; r < 16; ++r) acc[mg][ng][r] = 0.f;

    f32x4 st[8];

#define STAGE_LOAD(p)                                            \
    {                                                            \
        const float* sp_ = sbase + (p) * KPH;                    \
        _Pragma("unroll")                                        \
        for (int j = 0; j < 8; ++j) st[j] = ntload4(sp_ + j * 4);\
    }

#define STAGE_WRITE(p)                                                     \
    {                                                                      \
        unsigned short* dst_ = &Vs[(p) & 1][srow * KPH];                   \
        _Pragma("unroll")                                                  \
        for (int g = 0; g < 4; ++g) {                                      \
            u32 q0 = cvtpk(st[2 * g][0], st[2 * g][1]);                    \
            u32 q1 = cvtpk(st[2 * g][2], st[2 * g][3]);                    \
            u32 q2 = cvtpk(st[2 * g + 1][0], st[2 * g + 1][1]);            \
            u32 q3 = cvtpk(st[2 * g + 1][2], st[2 * g + 1][3]);            \
            i32x4 w_ = {(int)q0, (int)q1, (int)q2, (int)q3};               \
            *reinterpret_cast<i32x4*>(&dst_[(scol + g * 8) ^ swz]) = w_;   \
        }                                                                  \
    }

#define LOADA(p, kk, af)                                                        \
    {                                                                           \
        const unsigned short* ab_ = &Vs[(p) & 1][0];                            \
        const int k_ = (kk) * 16 + khalf;                                       \
        _Pragma("unroll")                                                       \
        for (int mg = 0; mg < 2; ++mg) {                                        \
            const int row_ = mg * 32 + col;                                     \
            af[mg] = *reinterpret_cast<const bf16x8*>(                          \
                &ab_[row_ * KPH + (k_ ^ ((row_ & 7) << 3))]);                   \
        }                                                                       \
    }

#define LOADB(p, kk, bf)                                                        \
    {                                                                           \
        const unsigned short* bb_ = wb + (p) * KPH + (kk) * 16;                 \
        _Pragma("unroll")                                                       \
        for (int ng = 0; ng < 4; ++ng)                                          \
            bf[ng] = *reinterpret_cast<const bf16x8*>(bb_ + (size_t)ng * 32 * DD); \
    }

    STAGE_LOAD(0);
    STAGE_WRITE(0);
    __syncthreads();

    for (int p = 0; p < NPH; ++p) {
        if (p + 1 < NPH) STAGE_LOAD(p + 1);  // in flight across compute

        bf16x8 aF[2][2], bF[2][4];
        LOADA(p, 0, aF[0]);
        LOADB(p, 0, bF[0]);
#pragma unroll
        for (int kk = 0; kk < 16; ++kk) {
            const int cur = kk & 1, nxt = cur ^ 1;
            if (kk < 15) {
                LOADA(p, kk + 1, aF[nxt]);
                LOADB(p, kk + 1, bF[nxt]);
            }
#pragma unroll
            for (int mg = 0; mg < 2; ++mg)
#pragma unroll
                for (int ng = 0; ng < 4; ++ng)
                    acc[mg][ng] = __builtin_amdgcn_mfma_f32_32x32x16_bf16(
                        aF[cur][mg], bF[cur][ng], acc[mg][ng], 0, 0, 0);
        }

        if (p + 1 < NPH) {
            __syncthreads();
            STAGE_WRITE(p + 1);
            __syncthreads();
        }
    }

    // epilogue: tanh + wv weighting
    float rs[2][16];
#pragma unroll
    for (int mg = 0; mg < 2; ++mg)
#pragma unroll
        for (int r = 0; r < 16; ++r) rs[mg][r] = 0.f;

#pragma unroll
    for (int ng = 0; ng < 4; ++ng) {
        const int u = nb + ng * 32 + col;
        const float qv = qp2[b * UU + u];
        const float wvv = wv[u];
#pragma unroll
        for (int mg = 0; mg < 2; ++mg)
#pragma unroll
            for (int r = 0; r < 16; ++r) {
                float h = acc[mg][ng][r] + qv;
                float e = __expf(2.f * h);
                float th = 1.f - 2.f / (e + 1.f);
                rs[mg][r] = fmaf(th, wvv, rs[mg][r]);
            }
    }

    // reduce over the 32 cols (lanes within each half)
#pragma unroll
    for (int mg = 0; mg < 2; ++mg)
#pragma unroll
        for (int r = 0; r < 16; ++r) {
            float v = rs[mg][r];
            v += __shfl_xor(v, 1);
            v += __shfl_xor(v, 2);
            v += __shfl_xor(v, 4);
            v += __shfl_xor(v, 8);
            v += __shfl_xor(v, 16);
            rs[mg][r] = v;
        }
    if ((lane & 31) == 0) {
        const int hi = lane >> 5;
#pragma unroll
        for (int mg = 0; mg < 2; ++mg)
#pragma unroll
            for (int r = 0; r < 16; ++r) {
                const int row = mg * 32 + (r & 3) + 8 * (r >> 2) + 4 * hi;
                ssum[wid][row] = rs[mg][r];
            }
    }
    __syncthreads();
    if (tid < MBLK) {
        float sc = bv[0];
#pragma unroll
        for (int w = 0; w < 8; ++w) sc += ssum[w][tid];
        score[b * SS + s0 + tid] = sc;
    }
#undef STAGE_LOAD
#undef STAGE_WRITE
#undef LOADA
#undef LOADB
}

// ---------------- K3a: softmax over S per batch ----------------
__global__ void softmax_kernel(const float* __restrict__ score, float* __restrict__ weights) {
    __shared__ float red[8];
    const int b = blockIdx.x;
    const int t = threadIdx.x;  // 256
    float local[8];
    float mx = -1e30f;
#pragma unroll
    for (int i = 0; i < 8; ++i) {
        local[i] = score[b * SS + i * 256 + t];
        mx = fmaxf(mx, local[i]);
    }
    for (int off = 1; off < 64; off <<= 1) mx = fmaxf(mx, __shfl_xor(mx, off));
    if ((t & 63) == 0) red[t >> 6] = mx;
    __syncthreads();
    const float m = fmaxf(fmaxf(red[0], red[1]), fmaxf(red[2], red[3]));
    float sum = 0.f;
#pragma unroll
    for (int i = 0; i < 8; ++i) {
        local[i] = __expf(local[i] - m);
        sum += local[i];
    }
    for (int off = 1; off < 64; off <<= 1) sum += __shfl_xor(sum, off);
    if ((t & 63) == 0) red[4 + (t >> 6)] = sum;
    __syncthreads();
    const float inv = 1.f / (red[4] + red[5] + red[6] + red[7]);
#pragma unroll
    for (int i = 0; i < 8; ++i) weights[b * SS + i * 256 + t] = local[i] * inv;
}

// ---------------- K3b: context[b,d] = sum_s w[b,s] * values[b,s,d] ----------------
__global__ void context_kernel(const float* __restrict__ values, const float* __restrict__ weights,
                               float* __restrict__ ctx) {
    __shared__ float ws[SS];          // 8 KB
    __shared__ f32x4 red[16][16];     // 4 KB
    const int b = blockIdx.x;   // 32
    const int dc = blockIdx.y;  // 16
    const int t = threadIdx.x;  // 256
    for (int i = t; i < SS; i += 256) ws[i] = weights[b * SS + i];
    __syncthreads();
    const int dt = t & 15;      // 16 d-threads (64 cols)
    const int ph = t >> 4;      // 16 s-phases
    const int d = dc * 64 + dt * 4;
    const float* vb = values + (size_t)b * SS * DD + d;
    f32x4 acc = {0.f, 0.f, 0.f, 0.f};
#pragma unroll 8
    for (int s = ph; s < SS; s += 16) {
        const float w = ws[s];
        f32x4 v = ntload4(vb + (size_t)s * DD);
        acc[0] = fmaf(w, v[0], acc[0]);
        acc[1] = fmaf(w, v[1], acc[1]);
        acc[2] = fmaf(w, v[2], acc[2]);
        acc[3] = fmaf(w, v[3], acc[3]);
    }
    red[ph][dt] = acc;
    __syncthreads();
    if (t < 16) {
        f32x4 r = red[0][t];
#pragma unroll
        for (int w = 1; w < 16; ++w) {
            f32x4 x = red[w][t];
#pragma unroll
            for (int i = 0; i < 4; ++i) r[i] += x[i];
        }
        *reinterpret_cast<f32x4*>(ctx + (size_t)b * DD + dc * 64 + t * 4) = r;
    }
}

extern "C" void kernel_launch(void* const* d_in, const int* in_sizes, int n_in,
                              void* d_out, int out_size, void* d_ws, size_t ws_size,
                              hipStream_t stream) {
    const float* query  = (const float*)d_in[0];
    const float* values = (const float*)d_in[1];
    const float* w1     = (const float*)d_in[2];
    const float* b1     = (const float*)d_in[3];
    const float* w2     = (const float*)d_in[4];
    const float* b2     = (const float*)d_in[5];
    const float* wv     = (const float*)d_in[6];
    const float* bv     = (const float*)d_in[7];

    float* ctx     = (float*)d_out;                    // [B, D]
    float* weights = (float*)d_out + (size_t)BB * DD;  // [B, S, 1]

    float* qp2           = (float*)d_ws;                                  // 128 KB
    unsigned short* w2t  = (unsigned short*)((char*)d_ws + 131072);       // 2 MB
    float* score         = (float*)((char*)d_ws + 131072 + 2097152);      // 256 KB

    qproj_kernel<<<dim3(BB, UU / 256), 256, 0, stream>>>(query, w1, b1, b2, qp2);
    w2t_kernel<<<dim3(UU / 64, DD / 64), 256, 0, stream>>>(w2, w2t);
    score_kernel<<<dim3(BB * SS / MBLK), 512, 0, stream>>>(values, w2t, qp2, wv, bv, score);
    softmax_kernel<<<dim3(BB), 256, 0, stream>>>(score, weights);
    context_kernel<<<dim3(BB, 16), 256, 0, stream>>>(values, weights, ctx);
}

// Round 6
// 503.227 us; speedup vs baseline: 1.0439x; 1.0439x over previous
//
#include <hip/hip_runtime.h>
#include <hip/hip_bf16.h>

#define BB 32
#define SS 2048
#define DD 1024
#define UU 1024
#define MBLK 64

typedef short bf16x8 __attribute__((ext_vector_type(8)));
typedef float f32x4 __attribute__((ext_vector_type(4)));
typedef int i32x4 __attribute__((ext_vector_type(4)));
typedef unsigned int u32;

__device__ __forceinline__ unsigned short f2bf(float x) {
    union { float f; unsigned int u; } v; v.f = x;
    unsigned int r = v.u + 0x7fffu + ((v.u >> 16) & 1u);
    return (unsigned short)(r >> 16);
}

__device__ __forceinline__ f32x4 ntload4(const float* p) {
    return __builtin_nontemporal_load(reinterpret_cast<const f32x4*>(p));
}

__device__ __forceinline__ u32 cvtpk(float lo, float hi) {
    u32 r;
    asm("v_cvt_pk_bf16_f32 %0, %1, %2" : "=v"(r) : "v"(lo), "v"(hi));
    return r;
}

// ---------------- K1a: q_proj = query@w1 + b1 + b2 ----------------
__global__ void qproj_kernel(const float* __restrict__ query, const float* __restrict__ w1,
                             const float* __restrict__ b1, const float* __restrict__ b2,
                             float* __restrict__ qp2) {
    __shared__ float qs[DD];
    const int b = blockIdx.x;   // 32
    const int uc = blockIdx.y;  // 4
    const int t = threadIdx.x;  // 256
    for (int i = t; i < DD; i += 256) qs[i] = query[b * DD + i];
    __syncthreads();
    const int u = uc * 256 + t;
    float acc = 0.f;
#pragma unroll 4
    for (int d = 0; d < DD; ++d) acc = fmaf(qs[d], w1[d * UU + u], acc);
    qp2[b * UU + u] = acc + b1[u] + b2[u];
}

// ---------------- K1b: w2t[u][d] = bf16(w2[d][u]) ----------------
__global__ void w2t_kernel(const float* __restrict__ w2, unsigned short* __restrict__ w2t) {
    __shared__ float tile[64][65];
    const int u0 = blockIdx.x * 64;
    const int d0 = blockIdx.y * 64;
    const int t = threadIdx.x;
    const int c = t & 63, rg = t >> 6;
#pragma unroll
    for (int rr = 0; rr < 16; ++rr) {
        int dl = rg * 16 + rr;
        tile[dl][c] = w2[(size_t)(d0 + dl) * UU + u0 + c];
    }
    __syncthreads();
#pragma unroll
    for (int rr = 0; rr < 16; ++rr) {
        int ul = rg * 16 + rr;
        w2t[(size_t)(u0 + ul) * DD + d0 + c] = f2bf(tile[c][ul]);
    }
}

// ---------------- K2: fused GEMM + tanh + wv-reduce -> score[b,s] ----------------
// 512 threads = 8 waves (2/SIMD). Full 64x1024 A-tile in LDS (128 KB), staged once.
// Then a BARRIER-FREE compute region: 2 U-passes x 32 kk, 16 MFMA each, with
// explicit depth-1 register prefetch of A (LDS) and B (L2). acc=64 VGPR (16x16x32),
// total ~170 VGPR -> no spill under launch_bounds(512,2).
__global__ __launch_bounds__(512, 2)
void score_kernel(const float* __restrict__ values, const unsigned short* __restrict__ w2t,
                  const float* __restrict__ qp2, const float* __restrict__ wv,
                  const float* __restrict__ bv, float* __restrict__ score) {
    __shared__ __align__(16) unsigned short Vs[MBLK * DD];  // 128 KB, XOR-swizzled
    __shared__ float ssum[8][MBLK];                          // 2 KB

    const int blk = blockIdx.x;       // 1024
    const int b = blk >> 5;
    const int s0 = (blk & 31) * MBLK;
    const int tid = threadIdx.x;
    const int lane = tid & 63;
    const int wid = tid >> 6;          // 0..7

    // ---- stage: 8 threads/row, 128 f32 each; f32 -> bf16 via cvt_pk; one barrier
    {
        const int srow = tid >> 3;           // 0..63
        const int scol = (tid & 7) * 128;    // 8 chunks of 128
        const int swz = (srow & 7) << 3;     // element-index XOR (16B granular)
        const float* src = values + ((size_t)b * SS + s0 + srow) * DD + scol;
        unsigned short* dst = &Vs[srow * DD];
#pragma unroll
        for (int j = 0; j < 4; ++j) {
            f32x4 st[8];
#pragma unroll
            for (int i = 0; i < 8; ++i) st[i] = ntload4(src + j * 32 + i * 4);
#pragma unroll
            for (int g = 0; g < 4; ++g) {
                u32 q0 = cvtpk(st[2 * g][0], st[2 * g][1]);
                u32 q1 = cvtpk(st[2 * g][2], st[2 * g][3]);
                u32 q2 = cvtpk(st[2 * g + 1][0], st[2 * g + 1][1]);
                u32 q3 = cvtpk(st[2 * g + 1][2], st[2 * g + 1][3]);
                i32x4 w_ = {(int)q0, (int)q1, (int)q2, (int)q3};
                *reinterpret_cast<i32x4*>(&dst[(scol + j * 32 + g * 8) ^ swz]) = w_;
            }
        }
    }
    __syncthreads();

    const int arow = lane & 15;        // frag row (A) / frag col (B, D)
    const int kgrp = (lane >> 4) * 8;  // k offset within frag

    float rowsum[16];
#pragma unroll
    for (int i = 0; i < 16; ++i) rowsum[i] = 0.f;

#define LOADA(kk, af)                                                       \
    {                                                                       \
        const int k_ = (kk) * 32 + kgrp;                                    \
        _Pragma("unroll")                                                   \
        for (int mf = 0; mf < 4; ++mf) {                                    \
            const int row_ = mf * 16 + arow;                                \
            af[mf] = *reinterpret_cast<const bf16x8*>(                      \
                &Vs[row_ * DD + (k_ ^ ((row_ & 7) << 3))]);                 \
        }                                                                   \
    }

#define LOADB(kk, bf)                                                       \
    {                                                                       \
        const unsigned short* bb_ = wbase + (kk) * 32;                      \
        _Pragma("unroll")                                                   \
        for (int nf = 0; nf < 4; ++nf)                                      \
            bf[nf] = *reinterpret_cast<const bf16x8*>(bb_ + (size_t)nf * 16 * DD); \
    }

#pragma unroll 1
    for (int p = 0; p < 2; ++p) {
        const int nb = (p * 8 + wid) * 64;  // this wave's 64-col U-slice
        const unsigned short* wbase = w2t + (size_t)(nb + arow) * DD + kgrp;

        f32x4 acc[4][4];
#pragma unroll
        for (int mf = 0; mf < 4; ++mf)
#pragma unroll
            for (int nf = 0; nf < 4; ++nf) { f32x4 z = {0.f, 0.f, 0.f, 0.f}; acc[mf][nf] = z; }

        bf16x8 aF[2][4], bF[2][4];
        LOADA(0, aF[0]);
        LOADB(0, bF[0]);
#pragma unroll 8
        for (int kk = 0; kk < 32; ++kk) {
            const int cur = kk & 1, nxt = cur ^ 1;
            if (kk < 31) {
                LOADA(kk + 1, aF[nxt]);
                LOADB(kk + 1, bF[nxt]);
            }
#pragma unroll
            for (int mf = 0; mf < 4; ++mf)
#pragma unroll
                for (int nf = 0; nf < 4; ++nf)
                    acc[mf][nf] = __builtin_amdgcn_mfma_f32_16x16x32_bf16(
                        aF[cur][mf], bF[cur][nf], acc[mf][nf], 0, 0, 0);
        }

        // per-pass epilogue: tanh + wv weighting into persistent rowsum
#pragma unroll
        for (int nf = 0; nf < 4; ++nf) {
            const int u = nb + nf * 16 + arow;
            const float qv = qp2[b * UU + u];
            const float wvv = wv[u];
#pragma unroll
            for (int mf = 0; mf < 4; ++mf)
#pragma unroll
                for (int i = 0; i < 4; ++i) {
                    float h = acc[mf][nf][i] + qv;
                    float e = __expf(2.f * h);
                    float th = 1.f - 2.f / (e + 1.f);
                    rowsum[mf * 4 + i] = fmaf(th, wvv, rowsum[mf * 4 + i]);
                }
        }
    }
#undef LOADA
#undef LOADB

    // reduce across the 16 lanes holding different cols of the same rows
#pragma unroll
    for (int i = 0; i < 16; ++i) {
        float v = rowsum[i];
        v += __shfl_xor(v, 1);
        v += __shfl_xor(v, 2);
        v += __shfl_xor(v, 4);
        v += __shfl_xor(v, 8);
        rowsum[i] = v;
    }
    if ((lane & 15) == 0) {
        const int rg = lane >> 4;  // row-group 0..3
#pragma unroll
        for (int mf = 0; mf < 4; ++mf)
#pragma unroll
            for (int i = 0; i < 4; ++i)
                ssum[wid][mf * 16 + rg * 4 + i] = rowsum[mf * 4 + i];
    }
    __syncthreads();
    if (tid < MBLK) {
        float sc = bv[0];
#pragma unroll
        for (int w = 0; w < 8; ++w) sc += ssum[w][tid];
        score[b * SS + s0 + tid] = sc;
    }
}

// ---------------- K3a: softmax over S per batch ----------------
__global__ void softmax_kernel(const float* __restrict__ score, float* __restrict__ weights) {
    __shared__ float red[8];
    const int b = blockIdx.x;
    const int t = threadIdx.x;  // 256
    float local[8];
    float mx = -1e30f;
#pragma unroll
    for (int i = 0; i < 8; ++i) {
        local[i] = score[b * SS + i * 256 + t];
        mx = fmaxf(mx, local[i]);
    }
    for (int off = 1; off < 64; off <<= 1) mx = fmaxf(mx, __shfl_xor(mx, off));
    if ((t & 63) == 0) red[t >> 6] = mx;
    __syncthreads();
    const float m = fmaxf(fmaxf(red[0], red[1]), fmaxf(red[2], red[3]));
    float sum = 0.f;
#pragma unroll
    for (int i = 0; i < 8; ++i) {
        local[i] = __expf(local[i] - m);
        sum += local[i];
    }
    for (int off = 1; off < 64; off <<= 1) sum += __shfl_xor(sum, off);
    if ((t & 63) == 0) red[4 + (t >> 6)] = sum;
    __syncthreads();
    const float inv = 1.f / (red[4] + red[5] + red[6] + red[7]);
#pragma unroll
    for (int i = 0; i < 8; ++i) weights[b * SS + i * 256 + t] = local[i] * inv;
}

// ---------------- K3b: context[b,d] = sum_s w[b,s] * values[b,s,d] ----------------
__global__ void context_kernel(const float* __restrict__ values, const float* __restrict__ weights,
                               float* __restrict__ ctx) {
    __shared__ float ws[SS];          // 8 KB
    __shared__ f32x4 red[16][16];     // 4 KB
    const int b = blockIdx.x;   // 32
    const int dc = blockIdx.y;  // 16
    const int t = threadIdx.x;  // 256
    for (int i = t; i < SS; i += 256) ws[i] = weights[b * SS + i];
    __syncthreads();
    const int dt = t & 15;      // 16 d-threads (64 cols)
    const int ph = t >> 4;      // 16 s-phases
    const int d = dc * 64 + dt * 4;
    const float* vb = values + (size_t)b * SS * DD + d;
    f32x4 acc = {0.f, 0.f, 0.f, 0.f};
#pragma unroll 8
    for (int s = ph; s < SS; s += 16) {
        const float w = ws[s];
        f32x4 v = ntload4(vb + (size_t)s * DD);
        acc[0] = fmaf(w, v[0], acc[0]);
        acc[1] = fmaf(w, v[1], acc[1]);
        acc[2] = fmaf(w, v[2], acc[2]);
        acc[3] = fmaf(w, v[3], acc[3]);
    }
    red[ph][dt] = acc;
    __syncthreads();
    if (t < 16) {
        f32x4 r = red[0][t];
#pragma unroll
        for (int w = 1; w < 16; ++w) {
            f32x4 x = red[w][t];
#pragma unroll
            for (int i = 0; i < 4; ++i) r[i] += x[i];
        }
        *reinterpret_cast<f32x4*>(ctx + (size_t)b * DD + dc * 64 + t * 4) = r;
    }
}

extern "C" void kernel_launch(void* const* d_in, const int* in_sizes, int n_in,
                              void* d_out, int out_size, void* d_ws, size_t ws_size,
                              hipStream_t stream) {
    const float* query  = (const float*)d_in[0];
    const float* values = (const float*)d_in[1];
    const float* w1     = (const float*)d_in[2];
    const float* b1     = (const float*)d_in[3];
    const float* w2     = (const float*)d_in[4];
    const float* b2     = (const float*)d_in[5];
    const float* wv     = (const float*)d_in[6];
    const float* bv     = (const float*)d_in[7];

    float* ctx     = (float*)d_out;                    // [B, D]
    float* weights = (float*)d_out + (size_t)BB * DD;  // [B, S, 1]

    float* qp2           = (float*)d_ws;                                  // 128 KB
    unsigned short* w2t  = (unsigned short*)((char*)d_ws + 131072);       // 2 MB
    float* score         = (float*)((char*)d_ws + 131072 + 2097152);      // 256 KB

    qproj_kernel<<<dim3(BB, UU / 256), 256, 0, stream>>>(query, w1, b1, b2, qp2);
    w2t_kernel<<<dim3(UU / 64, DD / 64), 256, 0, stream>>>(w2, w2t);
    score_kernel<<<dim3(BB * SS / MBLK), 512, 0, stream>>>(values, w2t, qp2, wv, bv, score);
    softmax_kernel<<<dim3(BB), 256, 0, stream>>>(score, weights);
    context_kernel<<<dim3(BB, 16), 256, 0, stream>>>(values, weights, ctx);
}